// Round 3
// baseline (145.099 us; speedup 1.0000x reference)
//
#include <hip/hip_runtime.h>

typedef __bf16 bf16x8 __attribute__((ext_vector_type(8)));
typedef float f32x4 __attribute__((ext_vector_type(4)));
typedef unsigned int uint4v __attribute__((ext_vector_type(4)));
typedef unsigned short ushort_t;
typedef unsigned int uint_t;

#define RS 0.08838834764831845f   // 1/sqrt(128)

__device__ __forceinline__ ushort_t f2bf(float f) {
    uint_t u = __float_as_uint(f);
    u += 0x7FFFu + ((u >> 16) & 1u);   // round-to-nearest-even
    return (ushort_t)(u >> 16);
}
__device__ __forceinline__ uint_t pack2(float a, float b) {
    return (uint_t)f2bf(a) | ((uint_t)f2bf(b) << 16);
}
union U4B8 { uint4v u; bf16x8 b; };
__device__ __forceinline__ bf16x8 as_bf(uint4v u) { U4B8 x; x.u = u; return x.b; }

// async global->LDS, 16B per lane; lds dest must be wave-uniform
__device__ __forceinline__ void pf16(const void* g, void* l) {
    __builtin_amdgcn_global_load_lds(
        (const __attribute__((address_space(1))) void*)g,
        (__attribute__((address_space(3))) void*)l, 16, 0, 0);
}

// padded xs frag addressing: frag stride 1072B (67x16), phase stride 272B (17x16)
__device__ __forceinline__ int xfrag(int f, int lane) {
    return f * 1072 + ((lane >> 4) * 272) + ((lane & 15) * 16);
}

// ---------------------------------------------------------------------------
// Fused prep (ONE dispatch): blocks 0..511 swizzle ops -> B-frag order
// (coalesced float4 reads, coalesced 16B writes); blocks 512..513 compute
// K' = keys@Wq into frag order and cb = keys@bq.
// frag(m,ks,dt): lane L holds ops[m][d=dt*16+(L&15)][e=ks*32+(L>>4)*8+j]
// ---------------------------------------------------------------------------
__global__ __launch_bounds__(256) void prep_kernel(
    const float* __restrict__ ops, const float* __restrict__ keys,
    const float* __restrict__ Wq, const float* __restrict__ bq,
    uint4v* __restrict__ ops_sw, ushort_t* __restrict__ kp_sw,
    float* __restrict__ cb)
{
    const int tid = threadIdx.x;
    const int b = blockIdx.x;
    if (b < 512) {
        int g = b * 256 + tid;     // [0, 131072)
        int L = g & 63, dt = (g >> 6) & 7, ks = (g >> 9) & 3, m = g >> 11;
        int d = dt * 16 + (L & 15);
        int e0 = ks * 32 + ((L >> 4) << 3);
        const float4* s = (const float4*)(ops + (((size_t)(m * 128 + d)) << 7) + e0);
        float4 v0 = s[0], v1 = s[1];
        uint4v o = { pack2(v0.x, v0.y), pack2(v0.z, v0.w),
                     pack2(v1.x, v1.y), pack2(v1.z, v1.w) };
        ops_sw[g] = o;
    } else {
        int d = tid & 127;
        int m0 = (b - 512) * 32 + (tid >> 7) * 16;
        float acc[16];
        #pragma unroll
        for (int i = 0; i < 16; ++i) acc[i] = 0.f;
        for (int e = 0; e < 128; ++e) {
            float wq = Wq[e * 128 + d];
            #pragma unroll
            for (int i = 0; i < 16; ++i)
                acc[i] = fmaf(keys[(m0 + i) * 128 + e], wq, acc[i]);
        }
        int ki = d >> 5, qq = (d >> 3) & 3, j = d & 7;
        #pragma unroll
        for (int i = 0; i < 16; ++i) {
            int m = m0 + i;
            kp_sw[((((ki * 4 + (m >> 4)) * 64) + (qq * 16 + (m & 15))) << 3) | j] = f2bf(acc[i]);
        }
        if (b == 512 && tid < 64) {
            float a2 = 0.f;
            for (int e = 0; e < 128; ++e)
                a2 = fmaf(bq[e], keys[tid * 128 + e], a2);
            cb[tid] = a2;
        }
    }
}

// ---------------------------------------------------------------------------
// Main: 512 blocks = 256 token-tiles x 2 d-halves. Block = 64 t x 64 d x ALL
// 64 slots -> complete result, direct stores (no atomics, no memset).
// Wave = 64 tokens x 16 d. A-frags in regs (64 VGPR). B streamed via
// global_load_lds into per-wave LDS double buffer — zero barriers in K-loop.
// Per slot: ds_read cur (vmcnt guard waits PREVIOUS slot's prefetch, hidden),
// issue prefetch nxt, sched_barrier, 16 MFMAs, attn-scale into C.
// ---------------------------------------------------------------------------
__global__ __launch_bounds__(256, 2) void main_kernel(
    const float* __restrict__ x, const float* __restrict__ cb,
    const ushort_t* __restrict__ kp_sw, const uint4v* __restrict__ ops_sw,
    float* __restrict__ out)
{
    __shared__ __align__(16) unsigned char xs[17152];        // padded A-frags
    __shared__ __align__(16) unsigned char bb[4][2][4096];   // per-wave B dbuf
    __shared__ float attn_f[64 * 68];                        // [slot][token]

    const int tid = threadIdx.x;
    const int lane = tid & 63;
    const int w = tid >> 6;
    const int q = lane >> 4;
    const int l15 = lane & 15;
    const int tb = blockIdx.x >> 1;
    const int dh = blockIdx.x & 1;
    const int t0 = tb * 64;
    const int dtw = dh * 4 + w;          // this wave's d-16-tile (0..7)

    // ---- Phase 1: stage x tile (64x128) -> bf16 A-frag order, bank-padded
    {
        const float4* x4 = (const float4*)(x + (size_t)t0 * 128);
        #pragma unroll
        for (int it = 0; it < 4; ++it) {
            int i = it * 256 + tid;
            int t = i >> 4, kc = i & 15;
            float4 a = x4[t * 32 + kc * 2];
            float4 b2 = x4[t * 32 + kc * 2 + 1];
            uint4v o = { pack2(a.x, a.y), pack2(a.z, a.w),
                         pack2(b2.x, b2.y), pack2(b2.z, b2.w) };
            *(uint4v*)(xs + ((t >> 4) * 4 + (kc >> 2)) * 1072
                          + (kc & 3) * 272 + (t & 15) * 16) = o;
        }
    }
    __syncthreads();

    // ---- Prologue: async-prefetch slot 0's B quarter into buf 0 (per-wave)
    const char* obase = (const char*)ops_sw + ((size_t)(dtw * 64 + lane) << 4);
    unsigned char* bw = &bb[w][0][0];
    #pragma unroll
    for (int ki = 0; ki < 4; ++ki)
        pf16(obase + ki * 8192, bw + ki * 1024);

    // ---- Phase 2: attention (wave w owns tokens w*16..w*16+15), all 64 slots
    {
        f32x4 L0 = {0,0,0,0}, L1 = {0,0,0,0}, L2 = {0,0,0,0}, L3 = {0,0,0,0};
        const uint4v* kpf = (const uint4v*)kp_sw;
        #pragma unroll
        for (int ki = 0; ki < 4; ++ki) {
            bf16x8 a = *(const bf16x8*)(xs + xfrag(w * 4 + ki, lane));
            L0 = __builtin_amdgcn_mfma_f32_16x16x32_bf16(a, as_bf(kpf[(ki*4+0)*64 + lane]), L0, 0,0,0);
            L1 = __builtin_amdgcn_mfma_f32_16x16x32_bf16(a, as_bf(kpf[(ki*4+1)*64 + lane]), L1, 0,0,0);
            L2 = __builtin_amdgcn_mfma_f32_16x16x32_bf16(a, as_bf(kpf[(ki*4+2)*64 + lane]), L2, 0,0,0);
            L3 = __builtin_amdgcn_mfma_f32_16x16x32_bf16(a, as_bf(kpf[(ki*4+3)*64 + lane]), L3, 0,0,0);
        }
        float c0 = cb[l15], c1 = cb[16 + l15], c2 = cb[32 + l15], c3 = cb[48 + l15];
        #pragma unroll
        for (int r = 0; r < 4; ++r) {
            float v0 = (L0[r] + c0) * RS;
            float v1 = (L1[r] + c1) * RS;
            float v2 = (L2[r] + c2) * RS;
            float v3 = (L3[r] + c3) * RS;
            float mx = fmaxf(fmaxf(v0, v1), fmaxf(v2, v3));
            #pragma unroll
            for (int off = 1; off < 16; off <<= 1) mx = fmaxf(mx, __shfl_xor(mx, off));
            float e0 = __expf(v0 - mx), e1 = __expf(v1 - mx),
                  e2 = __expf(v2 - mx), e3 = __expf(v3 - mx);
            float sm = e0 + e1 + e2 + e3;
            #pragma unroll
            for (int off = 1; off < 16; off <<= 1) sm += __shfl_xor(sm, off);
            float inv = 1.0f / sm;
            int t = w * 16 + q * 4 + r;
            attn_f[(     l15) * 68 + t] = e0 * inv;
            attn_f[(16 + l15) * 68 + t] = e1 * inv;
            attn_f[(32 + l15) * 68 + t] = e2 * inv;
            attn_f[(48 + l15) * 68 + t] = e3 * inv;
        }
    }

    // ---- A-frags for all 64 tokens into registers (64 VGPR), kept all K-loop
    bf16x8 A[4][4];
    #pragma unroll
    for (int tf = 0; tf < 4; ++tf)
        #pragma unroll
        for (int ki = 0; ki < 4; ++ki)
            A[tf][ki] = *(const bf16x8*)(xs + xfrag(tf * 4 + ki, lane));

    __syncthreads();

    // ---- Phase 3: 64 slots, LDS-DMA double-buffered, no barriers
    f32x4 C[4] = {};
    for (int ml = 0; ml < 64; ++ml) {
        const int cur = ml & 1;
        // wait the prefetch issued one slot ago (vmcnt(0); lgkm/exp unconstrained)
        __builtin_amdgcn_s_waitcnt(0x0F70);
        bf16x8 b0 = *(const bf16x8*)(bw + cur * 4096 +    0 + lane * 16);
        bf16x8 b1 = *(const bf16x8*)(bw + cur * 4096 + 1024 + lane * 16);
        bf16x8 b2 = *(const bf16x8*)(bw + cur * 4096 + 2048 + lane * 16);
        bf16x8 b3 = *(const bf16x8*)(bw + cur * 4096 + 3072 + lane * 16);
        if (ml < 63) {
            const char* src = obase + ((size_t)(ml + 1) << 15);
            unsigned char* dst = bw + (cur ^ 1) * 4096;
            #pragma unroll
            for (int ki = 0; ki < 4; ++ki)
                pf16(src + ki * 8192, dst + ki * 1024);
        }
        __builtin_amdgcn_sched_barrier(0);   // keep MFMAs after prefetch issue

        f32x4 S[4] = {};
        #pragma unroll
        for (int tf = 0; tf < 4; ++tf) {
            S[tf] = __builtin_amdgcn_mfma_f32_16x16x32_bf16(A[tf][0], b0, S[tf], 0,0,0);
            S[tf] = __builtin_amdgcn_mfma_f32_16x16x32_bf16(A[tf][1], b1, S[tf], 0,0,0);
            S[tf] = __builtin_amdgcn_mfma_f32_16x16x32_bf16(A[tf][2], b2, S[tf], 0,0,0);
            S[tf] = __builtin_amdgcn_mfma_f32_16x16x32_bf16(A[tf][3], b3, S[tf], 0,0,0);
        }
        #pragma unroll
        for (int tf = 0; tf < 4; ++tf) {
            f32x4 af = *(const f32x4*)&attn_f[ml * 68 + tf * 16 + q * 4];
            #pragma unroll
            for (int r = 0; r < 4; ++r)
                C[tf][r] = fmaf(af[r], S[tf][r], C[tf][r]);
        }
    }

    // ---- Epilogue: direct stores (complete sums; no atomics)
    float* op = out + (size_t)t0 * 128 + dh * 64 + w * 16 + l15;
    #pragma unroll
    for (int tf = 0; tf < 4; ++tf)
        #pragma unroll
        for (int r = 0; r < 4; ++r)
            op[(size_t)(tf * 16 + q * 4 + r) * 128] = C[tf][r];
}

// ---------------------------------------------------------------------------
extern "C" void kernel_launch(void* const* d_in, const int* in_sizes, int n_in,
                              void* d_out, int out_size, void* d_ws, size_t ws_size,
                              hipStream_t stream)
{
    const float* x    = (const float*)d_in[0];   // (4,4096,128)
    const float* keys = (const float*)d_in[1];   // (64,128)
    const float* ops  = (const float*)d_in[2];   // (64,128,128)
    const float* Wq   = (const float*)d_in[3];   // (128,128)
    const float* bq   = (const float*)d_in[4];   // (128,)
    float* out = (float*)d_out;

    char* ws = (char*)d_ws;
    uint4v*   ops_sw = (uint4v*)ws;                        // 2 MB
    ushort_t* kp_sw  = (ushort_t*)(ws + 2097152);          // 16 KB
    float*    cb     = (float*)(ws + 2097152 + 16384);     // 256 B

    prep_kernel<<<514, 256, 0, stream>>>(ops, keys, Wq, bq, ops_sw, kp_sw, cb);
    main_kernel<<<512, 256, 0, stream>>>(x, cb, kp_sw, ops_sw, out);
}

// Round 4
// 119.022 us; speedup vs baseline: 1.2191x; 1.2191x over previous
//
#include <hip/hip_runtime.h>

typedef __bf16 bf16x8 __attribute__((ext_vector_type(8)));
typedef float f32x4 __attribute__((ext_vector_type(4)));
typedef unsigned int uint4v __attribute__((ext_vector_type(4)));
typedef unsigned short ushort_t;
typedef unsigned int uint_t;

#define RS 0.08838834764831845f   // 1/sqrt(128)

__device__ __forceinline__ ushort_t f2bf(float f) {
    uint_t u = __float_as_uint(f);
    u += 0x7FFFu + ((u >> 16) & 1u);   // round-to-nearest-even
    return (ushort_t)(u >> 16);
}
__device__ __forceinline__ uint_t pack2(float a, float b) {
    return (uint_t)f2bf(a) | ((uint_t)f2bf(b) << 16);
}
union U4B8 { uint4v u; bf16x8 b; };
__device__ __forceinline__ bf16x8 as_bf(uint4v u) { U4B8 x; x.u = u; return x.b; }

// async global->LDS, 16B per lane; lds dest must be wave-uniform
__device__ __forceinline__ void pf16(const void* g, void* l) {
    __builtin_amdgcn_global_load_lds(
        (const __attribute__((address_space(1))) void*)g,
        (__attribute__((address_space(3))) void*)l, 16, 0, 0);
}

// padded xs frag addressing: frag stride 1072B (67x16), phase stride 272B (17x16)
__device__ __forceinline__ int xfrag(int f, int lane) {
    return f * 1072 + ((lane >> 4) * 272) + ((lane & 15) * 16);
}

// ---------------------------------------------------------------------------
// Prep (one dispatch, 576 blocks). Blocks 0..63: K'[m]=keys[m]@Wq via
// 2-way e-split over 256 threads + LDS reduce (NO serial 2-block tail — R3's
// 50us pathology), plus cb[m]=bq.keys[m] by wave-3 shuffle reduce.
// Blocks 64..575: swizzle ops -> bf16 B-frag order, coalesced in+out.
// frag(m,ks,dt): lane L holds ops[m][d=dt*16+(L&15)][e=ks*32+(L>>4)*8+j]
// ---------------------------------------------------------------------------
__global__ __launch_bounds__(256) void prep_kernel(
    const float* __restrict__ ops, const float* __restrict__ keys,
    const float* __restrict__ Wq, const float* __restrict__ bq,
    uint4v* __restrict__ ops_sw, ushort_t* __restrict__ kp_sw,
    float* __restrict__ cb)
{
    const int tid = threadIdx.x;
    const int b = blockIdx.x;
    if (b >= 64) {
        int g = (b - 64) * 256 + tid;     // [0, 131072)
        int L = g & 63, dt = (g >> 6) & 7, ks = (g >> 9) & 3, m = g >> 11;
        int d = dt * 16 + (L & 15);
        int e0 = ks * 32 + ((L >> 4) << 3);
        const float4* s = (const float4*)(ops + (((size_t)(m * 128 + d)) << 7) + e0);
        float4 v0 = s[0], v1 = s[1];
        uint4v o = { pack2(v0.x, v0.y), pack2(v0.z, v0.w),
                     pack2(v1.x, v1.y), pack2(v1.z, v1.w) };
        ops_sw[g] = o;
    } else {
        __shared__ float red[256];
        const int m = b;
        const int d = tid & 127, eh = tid >> 7;
        const float* kr = keys + m * 128 + eh * 64;
        const float* wc = Wq + (size_t)(eh * 64) * 128 + d;
        float acc = 0.f;
        #pragma unroll 8
        for (int e = 0; e < 64; ++e)
            acc = fmaf(kr[e], wc[(size_t)e * 128], acc);
        red[tid] = acc;
        __syncthreads();
        if (tid < 128) {
            float v = red[tid] + red[tid + 128];
            int ki = d >> 5, qq = (d >> 3) & 3, j = d & 7;
            kp_sw[((((ki * 4 + (m >> 4)) * 64) + (qq * 16 + (m & 15))) << 3) | j] = f2bf(v);
        } else if (tid >= 192) {
            int lane = tid - 192;
            float p = keys[m * 128 + lane] * bq[lane]
                    + keys[m * 128 + 64 + lane] * bq[64 + lane];
            #pragma unroll
            for (int off = 1; off < 64; off <<= 1) p += __shfl_xor(p, off);
            if (lane == 0) cb[m] = p;
        }
    }
}

// ---------------------------------------------------------------------------
// Main: 512 blocks = 256 token-tiles x 2 d-halves. Block = 64 t x 64 d x ALL
// 64 slots -> complete result, direct stores (no atomics, no memset).
// Wave = 64 tokens x 16 d. A-frags in regs. B streamed via global_load_lds
// into per-wave LDS double buffer — zero barriers in K-loop. Per slot:
// issue prefetch of slot ml+1 FIRST, then s_waitcnt vmcnt(4) (waits only the
// PREVIOUS slot's 4 loads; next loads stay in flight across the whole MFMA
// block — AITER-style never-zero vmcnt), sched_barrier to pin ds_reads below.
// ---------------------------------------------------------------------------
__global__ __launch_bounds__(256, 2) void main_kernel(
    const float* __restrict__ x, const float* __restrict__ cb,
    const ushort_t* __restrict__ kp_sw, const uint4v* __restrict__ ops_sw,
    float* __restrict__ out)
{
    __shared__ __align__(16) unsigned char xs[17152];        // padded A-frags
    __shared__ __align__(16) unsigned char bb[4][2][4096];   // per-wave B dbuf
    __shared__ float attn_f[64 * 68];                        // [slot][token]

    const int tid = threadIdx.x;
    const int lane = tid & 63;
    const int w = tid >> 6;
    const int q = lane >> 4;
    const int l15 = lane & 15;
    const int tb = blockIdx.x >> 1;
    const int dh = blockIdx.x & 1;
    const int t0 = tb * 64;
    const int dtw = dh * 4 + w;          // this wave's d-16-tile (0..7)

    // ---- Phase 1: stage x tile (64x128) -> bf16 A-frag order, bank-padded
    {
        const float4* x4 = (const float4*)(x + (size_t)t0 * 128);
        #pragma unroll
        for (int it = 0; it < 4; ++it) {
            int i = it * 256 + tid;
            int t = i >> 4, kc = i & 15;
            float4 a = x4[t * 32 + kc * 2];
            float4 b2 = x4[t * 32 + kc * 2 + 1];
            uint4v o = { pack2(a.x, a.y), pack2(a.z, a.w),
                         pack2(b2.x, b2.y), pack2(b2.z, b2.w) };
            *(uint4v*)(xs + ((t >> 4) * 4 + (kc >> 2)) * 1072
                          + (kc & 3) * 272 + (t & 15) * 16) = o;
        }
    }
    __syncthreads();

    // ---- Prologue: async-prefetch slot 0's B quarter into buf 0 (per-wave)
    const char* obase = (const char*)ops_sw + ((size_t)(dtw * 64 + lane) << 4);
    unsigned char* bw = &bb[w][0][0];
    #pragma unroll
    for (int ki = 0; ki < 4; ++ki)
        pf16(obase + ki * 8192, bw + ki * 1024);

    // ---- Phase 2: attention (wave w owns tokens w*16..w*16+15), all 64 slots
    {
        f32x4 L0 = {0,0,0,0}, L1 = {0,0,0,0}, L2 = {0,0,0,0}, L3 = {0,0,0,0};
        const uint4v* kpf = (const uint4v*)kp_sw;
        #pragma unroll
        for (int ki = 0; ki < 4; ++ki) {
            bf16x8 a = *(const bf16x8*)(xs + xfrag(w * 4 + ki, lane));
            L0 = __builtin_amdgcn_mfma_f32_16x16x32_bf16(a, as_bf(kpf[(ki*4+0)*64 + lane]), L0, 0,0,0);
            L1 = __builtin_amdgcn_mfma_f32_16x16x32_bf16(a, as_bf(kpf[(ki*4+1)*64 + lane]), L1, 0,0,0);
            L2 = __builtin_amdgcn_mfma_f32_16x16x32_bf16(a, as_bf(kpf[(ki*4+2)*64 + lane]), L2, 0,0,0);
            L3 = __builtin_amdgcn_mfma_f32_16x16x32_bf16(a, as_bf(kpf[(ki*4+3)*64 + lane]), L3, 0,0,0);
        }
        float c0 = cb[l15], c1 = cb[16 + l15], c2 = cb[32 + l15], c3 = cb[48 + l15];
        #pragma unroll
        for (int r = 0; r < 4; ++r) {
            float v0 = (L0[r] + c0) * RS;
            float v1 = (L1[r] + c1) * RS;
            float v2 = (L2[r] + c2) * RS;
            float v3 = (L3[r] + c3) * RS;
            float mx = fmaxf(fmaxf(v0, v1), fmaxf(v2, v3));
            #pragma unroll
            for (int off = 1; off < 16; off <<= 1) mx = fmaxf(mx, __shfl_xor(mx, off));
            float e0 = __expf(v0 - mx), e1 = __expf(v1 - mx),
                  e2 = __expf(v2 - mx), e3 = __expf(v3 - mx);
            float sm = e0 + e1 + e2 + e3;
            #pragma unroll
            for (int off = 1; off < 16; off <<= 1) sm += __shfl_xor(sm, off);
            float inv = 1.0f / sm;
            int t = w * 16 + q * 4 + r;
            attn_f[(     l15) * 68 + t] = e0 * inv;
            attn_f[(16 + l15) * 68 + t] = e1 * inv;
            attn_f[(32 + l15) * 68 + t] = e2 * inv;
            attn_f[(48 + l15) * 68 + t] = e3 * inv;
        }
    }

    // ---- A-frags for all 64 tokens into registers (64 VGPR), kept all K-loop
    bf16x8 A[4][4];
    #pragma unroll
    for (int tf = 0; tf < 4; ++tf)
        #pragma unroll
        for (int ki = 0; ki < 4; ++ki)
            A[tf][ki] = *(const bf16x8*)(xs + xfrag(tf * 4 + ki, lane));

    __syncthreads();

    // ---- Phase 3: 64 slots, LDS-DMA double-buffered, no barriers
    f32x4 C[4] = {};
    for (int ml = 0; ml < 64; ++ml) {
        const int cur = ml & 1;
        if (ml < 63) {
            // issue next slot's prefetch FIRST, then wait only the previous
            // slot's 4 loads (vmcnt(4)) — new loads stay in flight under MFMAs
            const char* src = obase + ((size_t)(ml + 1) << 15);
            unsigned char* dst = bw + (cur ^ 1) * 4096;
            #pragma unroll
            for (int ki = 0; ki < 4; ++ki)
                pf16(src + ki * 8192, dst + ki * 1024);
            __builtin_amdgcn_s_waitcnt(0x0F74);   // vmcnt(4)
        } else {
            __builtin_amdgcn_s_waitcnt(0x0F70);   // vmcnt(0)
        }
        __builtin_amdgcn_sched_barrier(0);        // ds_reads must stay below wait

        bf16x8 b0 = *(const bf16x8*)(bw + cur * 4096 +    0 + lane * 16);
        bf16x8 b1 = *(const bf16x8*)(bw + cur * 4096 + 1024 + lane * 16);
        bf16x8 b2 = *(const bf16x8*)(bw + cur * 4096 + 2048 + lane * 16);
        bf16x8 b3 = *(const bf16x8*)(bw + cur * 4096 + 3072 + lane * 16);

        f32x4 S[4] = {};
        #pragma unroll
        for (int tf = 0; tf < 4; ++tf) {
            S[tf] = __builtin_amdgcn_mfma_f32_16x16x32_bf16(A[tf][0], b0, S[tf], 0,0,0);
            S[tf] = __builtin_amdgcn_mfma_f32_16x16x32_bf16(A[tf][1], b1, S[tf], 0,0,0);
            S[tf] = __builtin_amdgcn_mfma_f32_16x16x32_bf16(A[tf][2], b2, S[tf], 0,0,0);
            S[tf] = __builtin_amdgcn_mfma_f32_16x16x32_bf16(A[tf][3], b3, S[tf], 0,0,0);
        }
        #pragma unroll
        for (int tf = 0; tf < 4; ++tf) {
            f32x4 af = *(const f32x4*)&attn_f[ml * 68 + tf * 16 + q * 4];
            #pragma unroll
            for (int r = 0; r < 4; ++r)
                C[tf][r] = fmaf(af[r], S[tf][r], C[tf][r]);
        }
    }

    // ---- Epilogue: direct stores (complete sums; no atomics)
    float* op = out + (size_t)t0 * 128 + dh * 64 + w * 16 + l15;
    #pragma unroll
    for (int tf = 0; tf < 4; ++tf)
        #pragma unroll
        for (int r = 0; r < 4; ++r)
            op[(size_t)(tf * 16 + q * 4 + r) * 128] = C[tf][r];
}

// ---------------------------------------------------------------------------
extern "C" void kernel_launch(void* const* d_in, const int* in_sizes, int n_in,
                              void* d_out, int out_size, void* d_ws, size_t ws_size,
                              hipStream_t stream)
{
    const float* x    = (const float*)d_in[0];   // (4,4096,128)
    const float* keys = (const float*)d_in[1];   // (64,128)
    const float* ops  = (const float*)d_in[2];   // (64,128,128)
    const float* Wq   = (const float*)d_in[3];   // (128,128)
    const float* bq   = (const float*)d_in[4];   // (128,)
    float* out = (float*)d_out;

    char* ws = (char*)d_ws;
    uint4v*   ops_sw = (uint4v*)ws;                        // 2 MB
    ushort_t* kp_sw  = (ushort_t*)(ws + 2097152);          // 16 KB
    float*    cb     = (float*)(ws + 2097152 + 16384);     // 256 B

    prep_kernel<<<576, 256, 0, stream>>>(ops, keys, Wq, bq, ops_sw, kp_sw, cb);
    main_kernel<<<512, 256, 0, stream>>>(x, cb, kp_sw, ops_sw, out);
}